// Round 2
// baseline (1475.589 us; speedup 1.0000x reference)
//
#include <hip/hip_runtime.h>
#include <hip/hip_bf16.h>

#define DEVINL __device__ __forceinline__

DEVINL float gelu_f(float x) {
    return 0.5f * x * (1.0f + erff(x * 0.70710678118654752440f));
}

// ---------------- S4D kernel precompute (f64 for phase accuracy) ----------------
// k[h,l] = 2*Re( sum_n Ck[h,n] * exp(dtA[h,n]*l) ),  Ck = C*(exp(dtA)-1)/A
__global__ __launch_bounds__(256)
void s4k_kernel(float* __restrict__ kout,
                const float* __restrict__ log_dt,
                const float* __restrict__ Cre,
                const float* __restrict__ Cim,
                const float* __restrict__ logAre,
                const float* __restrict__ Aim,
                int L)
{
    int idx = blockIdx.x * blockDim.x + threadIdx.x;
    int h = idx / L;
    int l = idx - h * L;
    if (h >= 128) return;
    double dt = exp((double)log_dt[h]);
    double acc = 0.0;
    const int N = 64;
    for (int n = 0; n < N; ++n) {
        double Ar = -exp((double)logAre[h * N + n]);
        double Ai = (double)Aim[h * N + n];
        double dr = Ar * dt, di = Ai * dt;         // dtA
        double edr = exp(dr);
        double sdi = sin(di), cdi = cos(di);
        double Er = edr * cdi - 1.0, Ei = edr * sdi;   // exp(dtA)-1
        double den = Ar * Ar + Ai * Ai;
        double tr = (Er * Ar + Ei * Ai) / den;         // (exp(dtA)-1)/A
        double ti = (Ei * Ar - Er * Ai) / den;
        double Cr = (double)Cre[h * N + n], Ci = (double)Cim[h * N + n];
        double ckr = Cr * tr - Ci * ti, cki = Cr * ti + Ci * tr;
        double mag = exp(dr * (double)l);
        double ph = di * (double)l;
        double zs = sin(ph), zc = cos(ph);
        acc += ckr * (mag * zc) - cki * (mag * zs);
    }
    kout[idx] = (float)(2.0 * acc);
}

// ---------------- generic f32 GEMM: C[m,n] = A[row(m),:] @ W[:,n] + bias ----------
// tiles: 64(M) x 128(N) x 32(K); 256 thr, each 4x8.
// gather: optional GLOBAL row indices for A (index = gather[m_base+m]).
// act: 0 none, 1 gelu.
// pool: if non-null, skip C store; atomicAdd block-partial row-means into
//       pool[((m_base+m0)/poolLen)*N + n]. Requires 64 | poolLen.
__global__ __launch_bounds__(256)
void gemm_kernel(const float* __restrict__ A, const int* __restrict__ gather,
                 const float* __restrict__ W, const float* __restrict__ bias,
                 float* __restrict__ C, float* __restrict__ pool,
                 long m_base, int K, int N, int act, int poolLen)
{
    __shared__ float As[32][68];     // [k][m]
    __shared__ float Ws[32][128];    // [k][n]
    __shared__ float red[16][128];

    int tid = threadIdx.x;
    int tx = tid & 15, ty = tid >> 4;
    long m0 = (long)blockIdx.x * 64;
    int n0 = blockIdx.y * 128;

    int la_row = tid >> 2, la_k = (tid & 3) * 8;
    long arow = gather ? (long)gather[m_base + m0 + la_row] : (m0 + la_row);
    const float* Arow = A + arow * (long)K + la_k;
    int wk = tid >> 3, wn = (tid & 7) * 16;
    const float* Wp = W + (long)wk * N + n0 + wn;

    float acc[4][8];
#pragma unroll
    for (int i = 0; i < 4; ++i)
#pragma unroll
        for (int j = 0; j < 8; ++j) acc[i][j] = 0.f;

    for (int k0 = 0; k0 < K; k0 += 32) {
        float4 a0 = *(const float4*)(Arow + k0);
        float4 a1 = *(const float4*)(Arow + k0 + 4);
        const float* wp = Wp + (long)k0 * N;
        float4 w0 = *(const float4*)(wp);
        float4 w1 = *(const float4*)(wp + 4);
        float4 w2 = *(const float4*)(wp + 8);
        float4 w3 = *(const float4*)(wp + 12);
        __syncthreads();
        As[la_k + 0][la_row] = a0.x; As[la_k + 1][la_row] = a0.y;
        As[la_k + 2][la_row] = a0.z; As[la_k + 3][la_row] = a0.w;
        As[la_k + 4][la_row] = a1.x; As[la_k + 5][la_row] = a1.y;
        As[la_k + 6][la_row] = a1.z; As[la_k + 7][la_row] = a1.w;
        *(float4*)&Ws[wk][wn]      = w0;
        *(float4*)&Ws[wk][wn + 4]  = w1;
        *(float4*)&Ws[wk][wn + 8]  = w2;
        *(float4*)&Ws[wk][wn + 12] = w3;
        __syncthreads();
#pragma unroll
        for (int kk = 0; kk < 32; ++kk) {
            float4 av  = *(const float4*)&As[kk][ty * 4];
            float4 wv0 = *(const float4*)&Ws[kk][tx * 4];        // cols tx*4..+3
            float4 wv1 = *(const float4*)&Ws[kk][64 + tx * 4];   // cols 64+tx*4..+3
            float a_[4] = {av.x, av.y, av.z, av.w};
            float w_[8] = {wv0.x, wv0.y, wv0.z, wv0.w, wv1.x, wv1.y, wv1.z, wv1.w};
#pragma unroll
            for (int i = 0; i < 4; ++i)
#pragma unroll
                for (int j = 0; j < 8; ++j)
                    acc[i][j] = fmaf(a_[i], w_[j], acc[i][j]);
        }
    }

    // column mapping: j<4 -> n0+tx*4+j ; j>=4 -> n0+64+tx*4+(j-4)
    float bv[8];
#pragma unroll
    for (int j = 0; j < 8; ++j) {
        int col = (j < 4) ? (tx * 4 + j) : (64 + tx * 4 + (j - 4));
        bv[j] = bias[n0 + col];
    }
#pragma unroll
    for (int i = 0; i < 4; ++i)
#pragma unroll
        for (int j = 0; j < 8; ++j) {
            float v = acc[i][j] + bv[j];
            if (act == 1) v = gelu_f(v);
            acc[i][j] = v;
        }

    if (pool) {
        float pv[8];
#pragma unroll
        for (int j = 0; j < 8; ++j)
            pv[j] = acc[0][j] + acc[1][j] + acc[2][j] + acc[3][j];
        __syncthreads();
#pragma unroll
        for (int j = 0; j < 8; ++j) {
            int col = (j < 4) ? (tx * 4 + j) : (64 + tx * 4 + (j - 4));
            red[ty][col] = pv[j];
        }
        __syncthreads();
        if (ty == 0) {
            long sent = (m_base + m0) / poolLen;
            float inv = 1.0f / (float)poolLen;
#pragma unroll
            for (int j = 0; j < 8; ++j) {
                int col = (j < 4) ? (tx * 4 + j) : (64 + tx * 4 + (j - 4));
                float s = 0.f;
#pragma unroll
                for (int t = 0; t < 16; ++t) s += red[t][col];
                atomicAdd(&pool[sent * N + n0 + col], s * inv);
            }
        }
    } else if (C) {
#pragma unroll
        for (int i = 0; i < 4; ++i) {
            long m = m0 + ty * 4 + i;
            float* cp = C + m * (long)N + n0;
            float4 s0 = {acc[i][0], acc[i][1], acc[i][2], acc[i][3]};
            float4 s1 = {acc[i][4], acc[i][5], acc[i][6], acc[i][7]};
            *(float4*)(cp + tx * 4) = s0;
            *(float4*)(cp + 64 + tx * 4) = s1;
        }
    }
}

// ---------------- transpose (b, l, h) token-major -> (b, h, l) ----------------
__global__ __launch_bounds__(256)
void transpose_kernel(const float* __restrict__ in, float* __restrict__ out,
                      int L, int H)
{
    __shared__ float t[32][33];
    int b = blockIdx.x, l0 = blockIdx.y * 32, h0 = blockIdx.z * 32;
    int tid = threadIdx.x;
    int c = tid & 31, r = tid >> 5;   // 8 rows/pass
    const float* ib = in + ((long)b * L + l0) * H + h0;
#pragma unroll
    for (int i = 0; i < 4; ++i)
        t[r + 8 * i][c] = ib[(long)(r + 8 * i) * H + c];      // t[l][h]
    __syncthreads();
    float* ob = out + ((long)b * H + h0) * L + l0;
#pragma unroll
    for (int i = 0; i < 4; ++i)
        ob[(long)(r + 8 * i) * L + c] = t[c][r + 8 * i];      // out[h][l]
}

// ---------------- causal Toeplitz conv: y[b,h,l] = sum_{j<=l} u[b,h,j]*k[h,l-j] --
// grid (h, b-tile 64, l-tile 64), block 256, thread 4(b)x4(l). H = 128.
__global__ __launch_bounds__(256)
void conv_kernel(const float* __restrict__ u, const float* __restrict__ kmat,
                 float* __restrict__ y, int NB, int L)
{
    __shared__ float Ut[64][68];    // [j][b]
    __shared__ float kwin[128];
    int h = blockIdx.x;
    int b0 = blockIdx.y * 64, l0 = blockIdx.z * 64;
    int tid = threadIdx.x, tx = tid & 15, ty = tid >> 4;
    const float* kh = kmat + (long)h * L;

    float acc[4][4];
#pragma unroll
    for (int i = 0; i < 4; ++i)
#pragma unroll
        for (int j = 0; j < 4; ++j) acc[i][j] = 0.f;

    int ur = tid >> 2, uc = (tid & 3) * 16;

    for (int j0 = 0; j0 <= l0 + 63; j0 += 64) {
        float4 u0 = {0,0,0,0}, u1 = {0,0,0,0}, u2 = {0,0,0,0}, u3 = {0,0,0,0};
        if (b0 + ur < NB) {
            const float* up = u + ((long)(b0 + ur) * 128 + h) * L + j0 + uc;
            u0 = *(const float4*)up;        u1 = *(const float4*)(up + 4);
            u2 = *(const float4*)(up + 8);  u3 = *(const float4*)(up + 12);
        }
        float kv_ = 0.f;
        int d = l0 - j0 - 63 + tid;
        if (tid < 128) kv_ = (d >= 0 && d < L) ? kh[d] : 0.f;
        __syncthreads();
        {
            float uv[16] = {u0.x,u0.y,u0.z,u0.w, u1.x,u1.y,u1.z,u1.w,
                            u2.x,u2.y,u2.z,u2.w, u3.x,u3.y,u3.z,u3.w};
#pragma unroll
            for (int q = 0; q < 16; ++q) Ut[uc + q][ur] = uv[q];
        }
        if (tid < 128) kwin[tid] = kv_;
        __syncthreads();
#pragma unroll
        for (int jj = 0; jj < 64; ++jj) {
            float4 uv = *(const float4*)&Ut[jj][ty * 4];
            float ub[4] = {uv.x, uv.y, uv.z, uv.w};
            float kj[4];
#pragma unroll
            for (int j = 0; j < 4; ++j) kj[j] = kwin[63 + tx * 4 + j - jj];
#pragma unroll
            for (int i = 0; i < 4; ++i)
#pragma unroll
                for (int j = 0; j < 4; ++j)
                    acc[i][j] = fmaf(ub[i], kj[j], acc[i][j]);
        }
    }
#pragma unroll
    for (int i = 0; i < 4; ++i) {
        int b = b0 + ty * 4 + i;
        if (b < NB) {
            float4 s = {acc[i][0], acc[i][1], acc[i][2], acc[i][3]};
            *(float4*)(y + ((long)b * 128 + h) * L + l0 + tx * 4) = s;
        }
    }
}

// ---------------- y = gelu(y + u*D[h]), (b,h,l) layout -----------------------
__global__ __launch_bounds__(256)
void skipgelu_kernel(float* __restrict__ y, const float* __restrict__ u,
                     const float* __restrict__ D, int log2L, long total)
{
    long i = (long)blockIdx.x * 256 + threadIdx.x;
    long stride = (long)gridDim.x * 256;
    for (; i < total; i += stride) {
        int h = (int)((i >> log2L) & 127);
        float v = y[i] + u[i] * D[h];
        y[i] = gelu_f(v);
    }
}

// ---------------- GLU 1x1 conv + residual, (b,h,l) layout. H = 128. ----------
// z[b,o,l] = (convW[o,:]@g + convb[o]) * sigmoid(convW[o+128,:]@g + convb[o+128]) + u[b,o,l]
// NOTE: z may alias u (element-wise read-before-write by the same thread), so
// u/z intentionally carry NO __restrict__.
__global__ __launch_bounds__(256)
void glu_kernel(const float* __restrict__ convW, const float* __restrict__ convb,
                const float* __restrict__ g, const float* u,
                float* z, int L)
{
    __shared__ float Wa[32][68], Wb[32][68], Gs[32][72];
    int b = blockIdx.x, o0 = blockIdx.y * 64, l0 = blockIdx.z * 64;
    int tid = threadIdx.x, tx = tid & 15, ty = tid >> 4;
    const float* gb = g + (long)b * 128 * L;

    float aa[4][4], ab[4][4];
#pragma unroll
    for (int i = 0; i < 4; ++i)
#pragma unroll
        for (int j = 0; j < 4; ++j) { aa[i][j] = 0.f; ab[i][j] = 0.f; }

    int wr = tid >> 2, wc = (tid & 3) * 8;
    int gh = tid >> 3, gl = (tid & 7) * 8;

    for (int k0 = 0; k0 < 128; k0 += 32) {
        float4 wa0 = *(const float4*)(convW + (long)(o0 + wr) * 128 + k0 + wc);
        float4 wa1 = *(const float4*)(convW + (long)(o0 + wr) * 128 + k0 + wc + 4);
        float4 wb0 = *(const float4*)(convW + (long)(o0 + wr + 128) * 128 + k0 + wc);
        float4 wb1 = *(const float4*)(convW + (long)(o0 + wr + 128) * 128 + k0 + wc + 4);
        float4 g0 = *(const float4*)(gb + (long)(k0 + gh) * L + l0 + gl);
        float4 g1 = *(const float4*)(gb + (long)(k0 + gh) * L + l0 + gl + 4);
        __syncthreads();
        {
            float wav[8] = {wa0.x,wa0.y,wa0.z,wa0.w, wa1.x,wa1.y,wa1.z,wa1.w};
            float wbv[8] = {wb0.x,wb0.y,wb0.z,wb0.w, wb1.x,wb1.y,wb1.z,wb1.w};
#pragma unroll
            for (int q = 0; q < 8; ++q) { Wa[wc + q][wr] = wav[q]; Wb[wc + q][wr] = wbv[q]; }
        }
        *(float4*)&Gs[gh][gl]     = g0;
        *(float4*)&Gs[gh][gl + 4] = g1;
        __syncthreads();
#pragma unroll
        for (int kk = 0; kk < 32; ++kk) {
            float4 wav = *(const float4*)&Wa[kk][ty * 4];
            float4 wbv = *(const float4*)&Wb[kk][ty * 4];
            float4 gv  = *(const float4*)&Gs[kk][tx * 4];
            float wa_[4] = {wav.x, wav.y, wav.z, wav.w};
            float wb_[4] = {wbv.x, wbv.y, wbv.z, wbv.w};
            float g_[4]  = {gv.x, gv.y, gv.z, gv.w};
#pragma unroll
            for (int i = 0; i < 4; ++i)
#pragma unroll
                for (int j = 0; j < 4; ++j) {
                    aa[i][j] = fmaf(wa_[i], g_[j], aa[i][j]);
                    ab[i][j] = fmaf(wb_[i], g_[j], ab[i][j]);
                }
        }
    }
#pragma unroll
    for (int i = 0; i < 4; ++i) {
        int o = o0 + ty * 4 + i;
        float ca = convb[o], cb2 = convb[o + 128];
        const float* up = u + ((long)b * 128 + o) * L + l0 + tx * 4;
        float4 uv = *(const float4*)up;
        float uu[4] = {uv.x, uv.y, uv.z, uv.w};
        float tmp[4];
#pragma unroll
        for (int j = 0; j < 4; ++j) {
            float av = aa[i][j] + ca;
            float bv = ab[i][j] + cb2;
            tmp[j] = av * (1.0f / (1.0f + expf(-bv))) + uu[j];
        }
        float4 outv = {tmp[0], tmp[1], tmp[2], tmp[3]};
        *(float4*)(z + ((long)b * 128 + o) * L + l0 + tx * 4) = outv;
    }
}

// ---------------- LayerNorm over H=128 + transpose to token-major ------------
// in z (b,h,l); out[(b*L+l), h] = (z - mu)/sqrt(var+eps)*gamma + beta
__global__ __launch_bounds__(256)
void ln_kernel(const float* __restrict__ z, const float* __restrict__ gamma,
               const float* __restrict__ beta, float* __restrict__ out, int L)
{
    __shared__ float zs[128][65];
    __shared__ float mu_s[64], rs_s[64];
    int b = blockIdx.x, l0 = blockIdx.y * 64;
    const float* zb = z + (long)b * 128 * L;
    int tid = threadIdx.x;
    for (int idx = tid; idx < 128 * 64; idx += 256) {
        int h = idx >> 6, li = idx & 63;
        zs[h][li] = zb[(long)h * L + l0 + li];
    }
    __syncthreads();
    int l = tid >> 2, sub = tid & 3;
    float s = 0.f, sq = 0.f;
    for (int ii = 0; ii < 32; ++ii) {
        int i = (ii + sub * 8) & 31;           // de-conflict banks
        float v = zs[sub * 32 + i][l];
        s += v; sq += v * v;
    }
    s += __shfl_xor(s, 1); sq += __shfl_xor(sq, 1);
    s += __shfl_xor(s, 2); sq += __shfl_xor(sq, 2);
    if (sub == 0) {
        float mu = s * (1.0f / 128.0f);
        float var = sq * (1.0f / 128.0f) - mu * mu;
        mu_s[l] = mu;
        rs_s[l] = rsqrtf(var + 1e-5f);
    }
    __syncthreads();
    for (int idx = tid; idx < 64 * 128; idx += 256) {
        int li = idx >> 7, h = idx & 127;
        float v = (zs[h][li] - mu_s[li]) * rs_s[li];
        out[((long)b * L + l0 + li) * 128 + h] = v * gamma[h] + beta[h];
    }
}

// =============================== host ========================================
extern "C" void kernel_launch(void* const* d_in, const int* in_sizes, int n_in,
                              void* d_out, int out_size, void* d_ws, size_t ws_size,
                              hipStream_t stream)
{
    const int* ids = (const int*)d_in[0];
    const float* emb = (const float*)d_in[1];
    const float* const* wp = (const float* const*)(d_in + 2);
    const float* const* sp = (const float* const*)(d_in + 18);
    enum {ENCW = 0, ENCB, LOGDT, CRE, CIM, LOGARE, AIM, DD,
          CONVW, CONVB, LNG, LNB, D1W, D1B, D2W, D2B};

    // ---- workspace arena (floats) ----
    // fixed small buffers: 794624 floats = 3.03 MB
    float* ws = (float*)d_ws;
    float* kW    = ws;                       // 128*512 = 65536
    float* kS    = kW + 65536;               // 128*64  = 8192
    float* sents = kS + 8192;                // 512*256 = 131072
    float* hbar  = sents + 131072;           // 512*256 = 131072
    float* su    = hbar + 131072;            // 512*128 = 65536
    float* subhl = su + 65536;
    float* sy    = subhl + 65536;
    float* szb   = sy + 65536;
    float* sxt   = szb + 65536;
    float* sh    = sxt + 65536;              // 512*256 = 131072
    float* big   = sh + 131072;
    const long SMALL = 794624;

    // chunk the word level over sentences so the big buffers fit ws_size.
    // per sentence: u (128*512) + y (128*512) = 131072 floats.
    long avail = (long)(ws_size / sizeof(float)) - SMALL;
    int SC = 512;
    while (SC > 1 && 2L * SC * 65536 > avail) SC >>= 1;
    int nch = 512 / SC;

    // ================= word level: 512 sents x L=512, H=128 =================
    hipMemsetAsync(hbar, 0, 131072 * sizeof(float), stream);
    s4k_kernel<<<256, 256, 0, stream>>>(
        kW, wp[LOGDT], wp[CRE], wp[CIM], wp[LOGARE], wp[AIM], 512);

    for (int c = 0; c < nch; ++c) {
        long tok_base = (long)c * SC * 512;          // global token offset
        float* u_c = big;                            // (SC,128,512)
        float* y_c = big + (long)SC * 65536;         // (SC,128,512) / token-major
        // embedding gather + encoder -> token-major into y_c
        gemm_kernel<<<dim3(SC * 8, 1), 256, 0, stream>>>(
            emb, ids, wp[ENCW], wp[ENCB], y_c, nullptr, tok_base, 256, 128, 0, 0);
        // token-major -> (b,h,l)
        transpose_kernel<<<dim3(SC, 16, 4), 256, 0, stream>>>(y_c, u_c, 512, 128);
        // causal conv u->y
        conv_kernel<<<dim3(128, (SC + 63) / 64, 8), 256, 0, stream>>>(
            u_c, kW, y_c, SC, 512);
        skipgelu_kernel<<<2048, 256, 0, stream>>>(
            y_c, u_c, wp[DD], 9, (long)SC * 65536);
        // GLU + residual: z overwrites u_c (alias-safe)
        glu_kernel<<<dim3(SC, 2, 8), 256, 0, stream>>>(
            wp[CONVW], wp[CONVB], y_c, u_c, u_c, 512);
        // LN -> token-major xt into y_c
        ln_kernel<<<dim3(SC, 8), 256, 0, stream>>>(u_c, wp[LNG], wp[LNB], y_c, 512);
        // d1 (gelu) with fused mean-pool over 512 words -> hbar
        gemm_kernel<<<dim3(SC * 8, 2), 256, 0, stream>>>(
            y_c, nullptr, wp[D1W], wp[D1B], nullptr, hbar, tok_base, 128, 256, 1, 512);
    }
    // d2 on pooled h: sents = hbar @ d2W + d2b   (pool-before-d2 is exact: d2 linear)
    gemm_kernel<<<dim3(8, 2), 256, 0, stream>>>(
        hbar, nullptr, wp[D2W], wp[D2B], sents, nullptr, 0, 256, 256, 0, 0);

    // ================= sentence level: B=8, L=64, H=128 =====================
    s4k_kernel<<<32, 256, 0, stream>>>(
        kS, sp[LOGDT], sp[CRE], sp[CIM], sp[LOGARE], sp[AIM], 64);
    gemm_kernel<<<dim3(8, 1), 256, 0, stream>>>(
        sents, nullptr, sp[ENCW], sp[ENCB], su, nullptr, 0, 256, 128, 0, 0);
    transpose_kernel<<<dim3(8, 2, 4), 256, 0, stream>>>(su, subhl, 64, 128);
    conv_kernel<<<dim3(128, 1, 1), 256, 0, stream>>>(subhl, kS, sy, 8, 64);
    skipgelu_kernel<<<256, 256, 0, stream>>>(sy, subhl, sp[DD], 6, 8L * 128 * 64);
    glu_kernel<<<dim3(8, 2, 1), 256, 0, stream>>>(
        sp[CONVW], sp[CONVB], sy, subhl, szb, 64);
    ln_kernel<<<dim3(8, 1), 256, 0, stream>>>(szb, sp[LNG], sp[LNB], sxt, 64);
    gemm_kernel<<<dim3(8, 2), 256, 0, stream>>>(
        sxt, nullptr, sp[D1W], sp[D1B], sh, nullptr, 0, 128, 256, 1, 0);
    gemm_kernel<<<dim3(8, 2), 256, 0, stream>>>(
        sh, nullptr, sp[D2W], sp[D2B], (float*)d_out, nullptr, 0, 256, 256, 0, 0);
}

// Round 5
// 676.942 us; speedup vs baseline: 2.1798x; 2.1798x over previous
//
#include <hip/hip_runtime.h>
#include <hip/hip_bf16.h>

#define DEVINL __device__ __forceinline__

typedef _Float16 f16;
typedef _Float16 f16x8 __attribute__((ext_vector_type(8)));
typedef float f32x4 __attribute__((ext_vector_type(4)));

#define MFMA16 __builtin_amdgcn_mfma_f32_16x16x32_f16

DEVINL float gelu_f(float x) {
    return 0.5f * x * (1.0f + erff(x * 0.70710678118654752440f));
}

// ---------------- S4D kernel precompute (f64 for phase accuracy) ----------------
__global__ __launch_bounds__(256)
void s4k_kernel(float* __restrict__ kout,
                const float* __restrict__ log_dt,
                const float* __restrict__ Cre,
                const float* __restrict__ Cim,
                const float* __restrict__ logAre,
                const float* __restrict__ Aim,
                int L)
{
    int idx = blockIdx.x * blockDim.x + threadIdx.x;
    int h = idx / L;
    int l = idx - h * L;
    if (h >= 128) return;
    double dt = exp((double)log_dt[h]);
    double acc = 0.0;
    const int N = 64;
    for (int n = 0; n < N; ++n) {
        double Ar = -exp((double)logAre[h * N + n]);
        double Ai = (double)Aim[h * N + n];
        double dr = Ar * dt, di = Ai * dt;
        double edr = exp(dr);
        double sdi = sin(di), cdi = cos(di);
        double Er = edr * cdi - 1.0, Ei = edr * sdi;
        double den = Ar * Ar + Ai * Ai;
        double tr = (Er * Ar + Ei * Ai) / den;
        double ti = (Ei * Ar - Er * Ai) / den;
        double Cr = (double)Cre[h * N + n], Ci = (double)Cim[h * N + n];
        double ckr = Cr * tr - Ci * ti, cki = Cr * ti + Ci * tr;
        double mag = exp(dr * (double)l);
        double ph = di * (double)l;
        acc += ckr * (mag * cos(ph)) - cki * (mag * sin(ph));
    }
    kout[idx] = (float)(2.0 * acc);
}

// ---------------- weight pack: f32 -> f16, optional transpose ----------------
// pack_t: dst[r][c] = src[c*R + r]  (dst R x C from src C x R)
__global__ __launch_bounds__(256)
void pack_t_kernel(f16* __restrict__ dst, const float* __restrict__ src,
                   int R, int C)
{
    int idx = blockIdx.x * 256 + threadIdx.x;
    int r = idx / C, c = idx - r * C;
    dst[idx] = (f16)src[c * R + r];
}
__global__ __launch_bounds__(256)
void pack_n_kernel(f16* __restrict__ dst, const float* __restrict__ src, int n)
{
    int idx = blockIdx.x * 256 + threadIdx.x;
    if (idx < n) dst[idx] = (f16)src[idx];
}

// ---------------- Toeplitz B-fragment precompute --------------------------------
// tf layout block = (((h*8+d)*2+s)*4+nn): [lane][r] = T[j][l] = k[h][64d + l - j],
//   j = 32 s + 8 (lane>>4) + r,  l = 16 nn + (lane&15); 0 outside [0,512).
__global__ __launch_bounds__(256)
void toep_kernel(f16* __restrict__ tf, const float* __restrict__ kW)
{
    int idx = blockIdx.x * 256 + threadIdx.x;      // 128*8*2*4*64*8 = 4194304
    int r = idx & 7;
    int lane = (idx >> 3) & 63;
    int nn = (idx >> 9) & 3;
    int s = (idx >> 11) & 1;
    int d = (idx >> 12) & 7;
    int h = idx >> 15;
    int widx = 64 * d + 16 * nn + (lane & 15) - 32 * s - 8 * (lane >> 4) - r;
    float v = (widx >= 0 && widx < 512) ? kW[h * 512 + widx] : 0.f;
    tf[idx] = (f16)v;
}

// ---------------- enc MFMA: gather emb rows, GEMM K=256 N=128, out (b,h,l) f16 --
__global__ __launch_bounds__(256)
void enc_mfma(const float* __restrict__ emb, const int* __restrict__ ids,
              long tok_base, const f16* __restrict__ WT /*[128][256]*/,
              const float* __restrict__ bias, f16* __restrict__ u /*(SC,128,512)*/)
{
    __shared__ f16 As[64][40];
    __shared__ f16 Bs[128][40];
    __shared__ f16 zs[128][72];
    int tid = threadIdx.x;
    int wave = tid >> 6, lane = tid & 63;
    long m0 = (long)blockIdx.x * 64;
    int b_local = (int)(m0 >> 9), l0 = (int)(m0 & 511);

    f32x4 acc[8] = {};

    int am = tid >> 2, aseg = tid & 3;
    int gidx = ids[tok_base + m0 + am];
    const float* aptr = emb + (long)gidx * 256 + aseg * 8;
    int bn = tid >> 1, bseg = tid & 1;
    const f16* bptr = WT + (long)bn * 256 + bseg * 16;

    for (int k0 = 0; k0 < 256; k0 += 32) {
        float4 a0 = *(const float4*)(aptr + k0);
        float4 a1 = *(const float4*)(aptr + k0 + 4);
        f16x8 b0 = *(const f16x8*)(bptr + k0);
        f16x8 b1 = *(const f16x8*)(bptr + k0 + 8);
        __syncthreads();
        f16x8 av;
        av[0]=(f16)a0.x; av[1]=(f16)a0.y; av[2]=(f16)a0.z; av[3]=(f16)a0.w;
        av[4]=(f16)a1.x; av[5]=(f16)a1.y; av[6]=(f16)a1.z; av[7]=(f16)a1.w;
        *(f16x8*)&As[am][aseg * 8] = av;
        *(f16x8*)&Bs[bn][bseg * 16] = b0;
        *(f16x8*)&Bs[bn][bseg * 16 + 8] = b1;
        __syncthreads();
        f16x8 af = *(const f16x8*)&As[16 * wave + (lane & 15)][8 * (lane >> 4)];
#pragma unroll
        for (int nn = 0; nn < 8; ++nn) {
            f16x8 bf = *(const f16x8*)&Bs[nn * 16 + (lane & 15)][8 * (lane >> 4)];
            acc[nn] = MFMA16(af, bf, acc[nn], 0, 0, 0);
        }
    }
    __syncthreads();
#pragma unroll
    for (int nn = 0; nn < 8; ++nn) {
        int h = nn * 16 + (lane & 15);
        float bv = bias[h];
#pragma unroll
        for (int reg = 0; reg < 4; ++reg) {
            int l = 16 * wave + 4 * (lane >> 4) + reg;
            zs[h][l] = (f16)(acc[nn][reg] + bv);
        }
    }
    __syncthreads();
    f16* ub = u + (long)b_local * 65536 + l0;
#pragma unroll
    for (int it = 0; it < 4; ++it) {
        int h = (tid >> 3) + 32 * it, seg = tid & 7;
        *(f16x8*)(ub + (long)h * 512 + seg * 8) = *(const f16x8*)&zs[h][seg * 8];
    }
}

// ---------------- conv MFMA: per-h Toeplitz GEMM + fused skip-gelu --------------
// y[b,h,l] = gelu( sum_j u[b,h,j] k[h,l-j] + u[b,h,l]*D[h] )
__global__ __launch_bounds__(256)
void conv_mfma(const f16* __restrict__ u, const f16* __restrict__ tf,
               const float* __restrict__ Dv, f16* __restrict__ y, int SC)
{
    __shared__ f16 As[64][72];
    __shared__ f16 ys[64][72];
    int h = blockIdx.x, b0 = blockIdx.y * 64, Lt = blockIdx.z;
    int l0 = Lt * 64;
    int tid = threadIdx.x, wave = tid >> 6, lane = tid & 63;

    f32x4 acc[4] = {};

    // staging: 64 rows x 64 j-cols; each thread loads 16 f16 (two f16x8)
    int ar = tid >> 2, aseg = tid & 3;
    bool arow_ok = (b0 + ar) < SC;
    const f16* ubase = u + ((long)(b0 + ar) * 128 + h) * 512;

    for (int jt = 0; jt <= Lt; ++jt) {
        f16x8 av0 = {}, av1 = {};
        if (arow_ok) {
            av0 = *(const f16x8*)(ubase + jt * 64 + aseg * 16);
            av1 = *(const f16x8*)(ubase + jt * 64 + aseg * 16 + 8);
        }
        __syncthreads();
        *(f16x8*)&As[ar][aseg * 16]     = av0;
        *(f16x8*)&As[ar][aseg * 16 + 8] = av1;
        __syncthreads();
        int d = Lt - jt;
        const f16* tfb = tf + (((long)h * 8 + d) * 8) * 512 + lane * 8;
#pragma unroll 2
        for (int s = 0; s < 2; ++s) {
            f16x8 af = *(const f16x8*)&As[16 * wave + (lane & 15)][32 * s + 8 * (lane >> 4)];
#pragma unroll
            for (int nn = 0; nn < 4; ++nn) {
                f16x8 bf = *(const f16x8*)(tfb + ((long)s * 4 + nn) * 512);
                acc[nn] = MFMA16(af, bf, acc[nn], 0, 0, 0);
            }
        }
    }
    // As now holds u[b, h, l0..l0+64) (jt == Lt tile)
    float Dh = Dv[h];
#pragma unroll
    for (int nn = 0; nn < 4; ++nn) {
#pragma unroll
        for (int reg = 0; reg < 4; ++reg) {
            int bl = 16 * wave + 4 * (lane >> 4) + reg;
            int ll = 16 * nn + (lane & 15);
            float uv = (float)As[bl][ll];
            ys[bl][ll] = (f16)gelu_f(acc[nn][reg] + uv * Dh);
        }
    }
    __syncthreads();
#pragma unroll
    for (int it = 0; it < 2; ++it) {
        int unit = tid + 256 * it;
        int r = unit >> 3, seg = unit & 7;
        if (b0 + r < SC)
            *(f16x8*)(y + ((long)(b0 + r) * 128 + h) * 512 + l0 + seg * 8)
                = *(const f16x8*)&ys[r][seg * 8];
    }
}

// ---------------- GLU MFMA + residual + fused LayerNorm -------------------------
// per (b, l-tile): z[l,o] = (convW[o,:]@y[:,l]+cb[o])*sig(convW[o+128,:]@y+cb[o+128]) + u[o,l]
// then LN over o (128), write xt token-major f16.
__global__ __launch_bounds__(256)
void glu_mfma(const f16* __restrict__ y, const f16* __restrict__ u,
              const f16* __restrict__ WT /*[256][128]*/,
              const float* __restrict__ cb, const float* __restrict__ lng,
              const float* __restrict__ lnb, f16* __restrict__ xt)
{
    __shared__ f16 At[64][136];
    __shared__ f16 Ut[64][136];
    __shared__ f16 Bs[256][40];
    int b = blockIdx.x, l0 = blockIdx.y * 64;
    int tid = threadIdx.x, wave = tid >> 6, lane = tid & 63;

    f32x4 acc[16] = {};

    // stage A^T (y) and U^T: [l][h]
#pragma unroll
    for (int it = 0; it < 4; ++it) {
        int unit = tid + 256 * it;
        int h = unit >> 3, seg = unit & 7;
        f16x8 v = *(const f16x8*)(y + ((long)b * 128 + h) * 512 + l0 + seg * 8);
        f16x8 w = *(const f16x8*)(u + ((long)b * 128 + h) * 512 + l0 + seg * 8);
#pragma unroll
        for (int q = 0; q < 8; ++q) {
            At[seg * 8 + q][h] = v[q];
            Ut[seg * 8 + q][h] = w[q];
        }
    }
    for (int k0 = 0; k0 < 128; k0 += 32) {
        f16x8 breg[4];
#pragma unroll
        for (int it = 0; it < 4; ++it) {
            int unit = tid + 256 * it;
            int n = unit >> 2, seg = unit & 3;
            breg[it] = *(const f16x8*)(WT + (long)n * 128 + k0 + seg * 8);
        }
        __syncthreads();
#pragma unroll
        for (int it = 0; it < 4; ++it) {
            int unit = tid + 256 * it;
            int n = unit >> 2, seg = unit & 3;
            *(f16x8*)&Bs[n][seg * 8] = breg[it];
        }
        __syncthreads();
        f16x8 af = *(const f16x8*)&At[16 * wave + (lane & 15)][k0 + 8 * (lane >> 4)];
#pragma unroll
        for (int nn = 0; nn < 16; ++nn) {
            f16x8 bf = *(const f16x8*)&Bs[nn * 16 + (lane & 15)][8 * (lane >> 4)];
            acc[nn] = MFMA16(af, bf, acc[nn], 0, 0, 0);
        }
    }
    // epilogue: GLU + residual, accumulate LN stats per row
    float zz[8][4];
    float sum[4] = {0.f, 0.f, 0.f, 0.f}, sq[4] = {0.f, 0.f, 0.f, 0.f};
#pragma unroll
    for (int nn = 0; nn < 8; ++nn) {
        int o = nn * 16 + (lane & 15);
        float ca = cb[o], cbb = cb[o + 128];
#pragma unroll
        for (int reg = 0; reg < 4; ++reg) {
            int l = 16 * wave + 4 * (lane >> 4) + reg;
            float a = acc[nn][reg] + ca;
            float bb = acc[nn + 8][reg] + cbb;
            float z = a * (1.0f / (1.0f + expf(-bb))) + (float)Ut[l][o];
            zz[nn][reg] = z;
            sum[reg] += z; sq[reg] += z * z;
        }
    }
#pragma unroll
    for (int d = 1; d < 16; d <<= 1) {
#pragma unroll
        for (int reg = 0; reg < 4; ++reg) {
            sum[reg] += __shfl_xor(sum[reg], d);
            sq[reg] += __shfl_xor(sq[reg], d);
        }
    }
    float mu[4], rs[4];
#pragma unroll
    for (int reg = 0; reg < 4; ++reg) {
        mu[reg] = sum[reg] * (1.0f / 128.0f);
        float var = sq[reg] * (1.0f / 128.0f) - mu[reg] * mu[reg];
        rs[reg] = rsqrtf(var + 1e-5f);
    }
    __syncthreads();   // all frag reads of At done; reuse as z-store
#pragma unroll
    for (int nn = 0; nn < 8; ++nn) {
        int o = nn * 16 + (lane & 15);
        float g = lng[o], bta = lnb[o];
#pragma unroll
        for (int reg = 0; reg < 4; ++reg) {
            int l = 16 * wave + 4 * (lane >> 4) + reg;
            At[l][o] = (f16)((zz[nn][reg] - mu[reg]) * rs[reg] * g + bta);
        }
    }
    __syncthreads();
    f16* xb = xt + ((long)b * 512 + l0) * 128;
#pragma unroll
    for (int it = 0; it < 4; ++it) {
        int unit = tid + 256 * it;
        int l = unit >> 4, seg = unit & 15;
        *(f16x8*)(xb + (long)l * 128 + seg * 8) = *(const f16x8*)&At[l][seg * 8];
    }
}

// ---------------- d1 MFMA + gelu + fused mean-pool ------------------------------
__global__ __launch_bounds__(256)
void d1_mfma(const f16* __restrict__ xt, const f16* __restrict__ WT /*[256][128]*/,
             const float* __restrict__ bias, float* __restrict__ hbar,
             long tok_base)
{
    __shared__ f16 At[64][136];
    __shared__ f16 Bs[256][40];
    __shared__ float red[4][16][16];
    int tid = threadIdx.x, wave = tid >> 6, lane = tid & 63;
    long m0 = (long)blockIdx.x * 64;

    f32x4 acc[16] = {};

#pragma unroll
    for (int it = 0; it < 4; ++it) {
        int unit = tid + 256 * it;
        int r = unit >> 4, seg = unit & 15;
        *(f16x8*)&At[r][seg * 8] = *(const f16x8*)(xt + (m0 + r) * 128 + seg * 8);
    }
    for (int k0 = 0; k0 < 128; k0 += 32) {
        f16x8 breg[4];
#pragma unroll
        for (int it = 0; it < 4; ++it) {
            int unit = tid + 256 * it;
            int n = unit >> 2, seg = unit & 3;
            breg[it] = *(const f16x8*)(WT + (long)n * 128 + k0 + seg * 8);
        }
        __syncthreads();
#pragma unroll
        for (int it = 0; it < 4; ++it) {
            int unit = tid + 256 * it;
            int n = unit >> 2, seg = unit & 3;
            *(f16x8*)&Bs[n][seg * 8] = breg[it];
        }
        __syncthreads();
        f16x8 af = *(const f16x8*)&At[16 * wave + (lane & 15)][k0 + 8 * (lane >> 4)];
#pragma unroll
        for (int nn = 0; nn < 16; ++nn) {
            f16x8 bf = *(const f16x8*)&Bs[nn * 16 + (lane & 15)][8 * (lane >> 4)];
            acc[nn] = MFMA16(af, bf, acc[nn], 0, 0, 0);
        }
    }
    long sent = (tok_base + m0) >> 9;
#pragma unroll
    for (int nn = 0; nn < 16; ++nn) {
        int o = nn * 16 + (lane & 15);
        float bv = bias[o];
        float s = 0.f;
#pragma unroll
        for (int reg = 0; reg < 4; ++reg)
            s += gelu_f(acc[nn][reg] + bv);
        s += __shfl_xor(s, 16);
        s += __shfl_xor(s, 32);
        if (lane < 16) red[wave][lane][nn] = s;
    }
    __syncthreads();
    if (wave == 0 && lane < 16) {
#pragma unroll
        for (int nn = 0; nn < 16; ++nn) {
            float tot = red[0][lane][nn] + red[1][lane][nn]
                      + red[2][lane][nn] + red[3][lane][nn];
            atomicAdd(&hbar[sent * 256 + nn * 16 + lane], tot * (1.0f / 512.0f));
        }
    }
}

// ======================= f32 kernels (sentence level + d2) ======================
__global__ __launch_bounds__(256)
void gemm_kernel(const float* __restrict__ A, const int* __restrict__ gather,
                 const float* __restrict__ W, const float* __restrict__ bias,
                 float* __restrict__ C, float* __restrict__ pool,
                 long m_base, int K, int N, int act, int poolLen)
{
    __shared__ float As[32][68];
    __shared__ float Ws[32][128];
    __shared__ float red[16][128];

    int tid = threadIdx.x;
    int tx = tid & 15, ty = tid >> 4;
    long m0 = (long)blockIdx.x * 64;
    int n0 = blockIdx.y * 128;

    int la_row = tid >> 2, la_k = (tid & 3) * 8;
    long arow = gather ? (long)gather[m_base + m0 + la_row] : (m0 + la_row);
    const float* Arow = A + arow * (long)K + la_k;
    int wk = tid >> 3, wn = (tid & 7) * 16;
    const float* Wp = W + (long)wk * N + n0 + wn;

    float acc[4][8];
#pragma unroll
    for (int i = 0; i < 4; ++i)
#pragma unroll
        for (int j = 0; j < 8; ++j) acc[i][j] = 0.f;

    for (int k0 = 0; k0 < K; k0 += 32) {
        float4 a0 = *(const float4*)(Arow + k0);
        float4 a1 = *(const float4*)(Arow + k0 + 4);
        const float* wp = Wp + (long)k0 * N;
        float4 w0 = *(const float4*)(wp);
        float4 w1 = *(const float4*)(wp + 4);
        float4 w2 = *(const float4*)(wp + 8);
        float4 w3 = *(const float4*)(wp + 12);
        __syncthreads();
        As[la_k + 0][la_row] = a0.x; As[la_k + 1][la_row] = a0.y;
        As[la_k + 2][la_row] = a0.z; As[la_k + 3][la_row] = a0.w;
        As[la_k + 4][la_row] = a1.x; As[la_k + 5][la_row] = a1.y;
        As[la_k + 6][la_row] = a1.z; As[la_k + 7][la_row] = a1.w;
        *(float4*)&Ws[wk][wn]      = w0;
        *(float4*)&Ws[wk][wn + 4]  = w1;
        *(float4*)&Ws[wk][wn + 8]  = w2;
        *(float4*)&Ws[wk][wn + 12] = w3;
        __syncthreads();
#pragma unroll
        for (int kk = 0; kk < 32; ++kk) {
            float4 av  = *(const float4*)&As[kk][ty * 4];
            float4 wv0 = *(const float4*)&Ws[kk][tx * 4];
            float4 wv1 = *(const float4*)&Ws[kk][64 + tx * 4];
            float a_[4] = {av.x, av.y, av.z, av.w};
            float w_[8] = {wv0.x, wv0.y, wv0.z, wv0.w, wv1.x, wv1.y, wv1.z, wv1.w};
#pragma unroll
            for (int i = 0; i < 4; ++i)
#pragma unroll
                for (int j = 0; j < 8; ++j)
                    acc[i][j] = fmaf(a_[i], w_[j], acc[i][j]);
        }
    }

    float bv[8];
#pragma unroll
    for (int j = 0; j < 8; ++j) {
        int col = (j < 4) ? (tx * 4 + j) : (64 + tx * 4 + (j - 4));
        bv[j] = bias[n0 + col];
    }
#pragma unroll
    for (int i = 0; i < 4; ++i)
#pragma unroll
        for (int j = 0; j < 8; ++j) {
            float v = acc[i][j] + bv[j];
            if (act == 1) v = gelu_f(v);
            acc[i][j] = v;
        }

    if (pool) {
        float pv[8];
#pragma unroll
        for (int j = 0; j < 8; ++j)
            pv[j] = acc[0][j] + acc[1][j] + acc[2][j] + acc[3][j];
        __syncthreads();
#pragma unroll
        for (int j = 0; j < 8; ++j) {
            int col = (j < 4) ? (tx * 4 + j) : (64 + tx * 4 + (j - 4));
            red[ty][col] = pv[j];
        }
        __syncthreads();
        if (ty == 0) {
            long sent = (m_base + m0) / poolLen;
            float inv = 1.0f / (float)poolLen;
#pragma unroll
            for (int j = 0; j < 8; ++j) {
                int col = (j < 4) ? (tx * 4 + j) : (64 + tx * 4 + (j - 4));
                float s = 0.f;
#pragma unroll
                for (int t = 0; t < 16; ++t) s += red[t][col];
                atomicAdd(&pool[sent * N + n0 + col], s * inv);
            }
        }
    } else if (C) {
#pragma unroll
        for (int i = 0; i < 4; ++i) {
            long m = m0 + ty * 4 + i;
            float* cp = C + m * (long)N + n0;
            float4 s0 = {acc[i][0], acc[i][1], acc[i][2], acc[i][3]};
            float4 s1 = {acc[i][4], acc[i][5], acc[i][6], acc[i][7]};
            *(float4*)(cp + tx * 4) = s0;
            *(float4*)(cp + 64 + tx * 4) = s1;
        }
    }
}

__global__ __launch_bounds__(256)
void transpose_kernel(const float* __restrict__ in, float* __restrict__ out,
                      int L, int H)
{
    __shared__ float t[32][33];
    int b = blockIdx.x, l0 = blockIdx.y * 32, h0 = blockIdx.z * 32;
    int tid = threadIdx.x;
    int c = tid & 31, r = tid >> 5;
    const float* ib = in + ((long)b * L + l0) * H + h0;
#pragma unroll
    for (int i = 0; i < 4; ++i)
        t[r + 8 * i][c] = ib[(long)(r + 8 * i) * H + c];
    __syncthreads();
    float* ob = out + ((long)b * H + h0) * L + l0;
#pragma unroll
    for (int i = 0; i < 4; ++i)
        ob[(long)(r + 8 * i) * L + c] = t[c][r + 8 * i];
}

__global__ __launch_bounds__(256)
void conv_kernel(const float* __restrict__ u, const float* __restrict__ kmat,
                 float* __restrict__ y, int NB, int L)
{
    __shared__ float Ut[64][68];
    __shared__ float kwin[128];
    int h = blockIdx.x;
    int b0 = blockIdx.y * 64, l0 = blockIdx.z * 64;
    int tid = threadIdx.x, tx = tid & 15, ty = tid >> 4;
    const float* kh = kmat + (long)h * L;

    float acc[4][4];
#pragma unroll
    for (int i = 0; i < 4; ++i)
#pragma unroll
        for (int j = 0; j < 4; ++j) acc[i][j] = 0.f;

    int ur = tid >> 2, uc = (tid & 3) * 16;

    for (int j0 = 0; j0 <= l0 + 63; j0 += 64) {
        float4 u0 = {0,0,0,0}, u1 = {0,0,0,0}, u2 = {0,0,0,0}, u3 = {0,0,0,0};
        if (b0 + ur < NB) {
            const float* up = u + ((long)(b0 + ur) * 128 + h) * L + j0 + uc;
            u0 = *(const float4*)up;        u1 = *(const float4*)(up + 4);
            u2 = *(const float4*)(up + 8);  u3 = *(const float4*)(up + 12);
        }
        float kv_ = 0.f;
        int d = l0 - j0 - 63 + tid;
        if (tid < 128) kv_ = (d >= 0 && d < L) ? kh[d] : 0.f;
        __syncthreads();
        {
            float uv[16] = {u0.x,u0.y,u0.z,u0.w, u1.x,u1.y,u1.z,u1.w,
                            u2.x,u2.y,u2.z,u2.w, u3.x,u3.y,u3.z,u3.w};
#pragma unroll
            for (int q = 0; q < 16; ++q) Ut[uc + q][ur] = uv[q];
        }
        if (tid < 128) kwin[tid] = kv_;
        __syncthreads();
#pragma unroll
        for (int jj = 0; jj < 64; ++jj) {
            float4 uv = *(const float4*)&Ut[jj][ty * 4];
            float ub[4] = {uv.x, uv.y, uv.z, uv.w};
            float kj[4];
#pragma unroll
            for (int j = 0; j < 4; ++j) kj[j] = kwin[63 + tx * 4 + j - jj];
#pragma unroll
            for (int i = 0; i < 4; ++i)
#pragma unroll
                for (int j = 0; j < 4; ++j)
                    acc[i][j] = fmaf(ub[i], kj[j], acc[i][j]);
        }
    }
#pragma unroll
    for (int i = 0; i < 4; ++i) {
        int b = b0 + ty * 4 + i;
        if (b < NB) {
            float4 s = {acc[i][0], acc[i][1], acc[i][2], acc[i][3]};
            *(float4*)(y + ((long)b * 128 + h) * L + l0 + tx * 4) = s;
        }
    }
}

__global__ __launch_bounds__(256)
void skipgelu_kernel(float* __restrict__ y, const float* __restrict__ u,
                     const float* __restrict__ D, int log2L, long total)
{
    long i = (long)blockIdx.x * 256 + threadIdx.x;
    long stride = (long)gridDim.x * 256;
    for (; i < total; i += stride) {
        int h = (int)((i >> log2L) & 127);
        float v = y[i] + u[i] * D[h];
        y[i] = gelu_f(v);
    }
}

__global__ __launch_bounds__(256)
void glu_kernel(const float* __restrict__ convW, const float* __restrict__ convb,
                const float* __restrict__ g, const float* u,
                float* z, int L)
{
    __shared__ float Wa[32][68], Wb[32][68], Gs[32][72];
    int b = blockIdx.x, o0 = blockIdx.y * 64, l0 = blockIdx.z * 64;
    int tid = threadIdx.x, tx = tid & 15, ty = tid >> 4;
    const float* gb = g + (long)b * 128 * L;

    float aa[4][4], ab[4][4];
#pragma unroll
    for (int i = 0; i < 4; ++i)
#pragma unroll
        for (int j = 0; j < 4; ++j) { aa[i][j] = 0.f; ab[i][j] = 0.f; }

    int wr = tid >> 2, wc = (tid & 3) * 8;
    int gh = tid >> 3, gl = (tid & 7) * 8;

    for (int k0 = 0; k0 < 128; k0 += 32) {
        float4 wa0 = *(const float4*)(convW + (long)(o0 + wr) * 128 + k0 + wc);
        float4 wa1 = *(const float4*)(convW + (long)(o0 + wr) * 128 + k0 + wc + 4);
        float4 wb0 = *(const float4*)(convW + (long)(o0 + wr + 128) * 128 + k0 + wc);
        float4 wb1 = *(const float4*)(convW + (long)(o0 + wr + 128) * 128 + k0 + wc + 4);
        float4 g0 = *(const float4*)(gb + (long)(k0 + gh) * L + l0 + gl);
        float4 g1 = *(const float4*)(gb + (long)(k0 + gh) * L + l0 + gl + 4);
        __syncthreads();
        {
            float wav[8] = {wa0.x,wa0.y,wa0.z,wa0.w, wa1.x,wa1.y,wa1.z,wa1.w};
            float wbv[8] = {wb0.x,wb0.y,wb0.z,wb0.w, wb1.x,wb1.y,wb1.z,wb1.w};
#pragma unroll
            for (int q = 0; q < 8; ++q) { Wa[wc + q][wr] = wav[q]; Wb[wc + q][wr] = wbv[q]; }
        }
        *(float4*)&Gs[gh][gl]     = g0;
        *(float4*)&Gs[gh][gl + 4] = g1;
        __syncthreads();
#pragma unroll
        for (int kk = 0; kk < 32; ++kk) {
            float4 wav = *(const float4*)&Wa[kk][ty * 4];
            float4 wbv = *(const float4*)&Wb[kk][ty * 4];
            float4 gv  = *(const float4*)&Gs[kk][tx * 4];
            float wa_[4] = {wav.x, wav.y, wav.z, wav.w};
            float wb_[4] = {wbv.x, wbv.y, wbv.z, wbv.w};
            float g_[4]  = {gv.x, gv.y, gv.z, gv.w};
#pragma unroll
            for (int i = 0; i < 4; ++i)
#pragma unroll
                for (int j = 0; j < 4; ++j) {
                    aa[i][j] = fmaf(wa_[i], g_[j], aa[i][j]);
                    ab[i][j] = fmaf(wb_[i], g_[j], ab[i][j]);
                }
        }
    }
#pragma unroll
    for (int i = 0; i < 4; ++i) {
        int o = o0 + ty * 4 + i;
        float ca = convb[o], cb2 = convb[o + 128];
        const float* up = u + ((long)b * 128 + o) * L + l0 + tx * 4;
        float4 uv = *(const float4*)up;
        float uu[4] = {uv.x, uv.y, uv.z, uv.w};
        float tmp[4];
#pragma unroll
        for (int j = 0; j < 4; ++j) {
            float av = aa[i][j] + ca;
            float bv2 = ab[i][j] + cb2;
            tmp[j] = av * (1.0f / (1.0f + expf(-bv2))) + uu[j];
        }
        float4 outv = {tmp[0], tmp[1], tmp[2], tmp[3]};
        *(float4*)(z + ((long)b * 128 + o) * L + l0 + tx * 4) = outv;
    }
}

__global__ __launch_bounds__(256)
void ln_kernel(const float* __restrict__ z, const float* __restrict__ gamma,
               const float* __restrict__ beta, float* __restrict__ out, int L)
{
    __shared__ float zs[128][65];
    __shared__ float mu_s[64], rs_s[64];
    int b = blockIdx.x, l0 = blockIdx.y * 64;
    const float* zb = z + (long)b * 128 * L;
    int tid = threadIdx.x;
    for (int idx = tid; idx < 128 * 64; idx += 256) {
        int h = idx >> 6, li = idx & 63;
        zs[h][li] = zb[(long)h * L + l0 + li];
    }
    __syncthreads();
    int l = tid >> 2, sub = tid & 3;
    float s = 0.f, sq = 0.f;
    for (int ii = 0; ii < 32; ++ii) {
        int i = (ii + sub * 8) & 31;
        float v = zs[sub * 32 + i][l];
        s += v; sq += v * v;
    }
    s += __shfl_xor(s, 1); sq += __shfl_xor(sq, 1);
    s += __shfl_xor(s, 2); sq += __shfl_xor(sq, 2);
    if (sub == 0) {
        float mu = s * (1.0f / 128.0f);
        float var = sq * (1.0f / 128.0f) - mu * mu;
        mu_s[l] = mu;
        rs_s[l] = rsqrtf(var + 1e-5f);
    }
    __syncthreads();
    for (int idx = tid; idx < 64 * 128; idx += 256) {
        int li = idx >> 7, h = idx & 127;
        float v = (zs[h][li] - mu_s[li]) * rs_s[li];
        out[((long)b * L + l0 + li) * 128 + h] = v * gamma[h] + beta[h];
    }
}

// =============================== host ========================================
extern "C" void kernel_launch(void* const* d_in, const int* in_sizes, int n_in,
                              void* d_out, int out_size, void* d_ws, size_t ws_size,
                              hipStream_t stream)
{
    const int* ids = (const int*)d_in[0];
    const float* emb = (const float*)d_in[1];
    const float* const* wp = (const float* const*)(d_in + 2);
    const float* const* sp = (const float* const*)(d_in + 18);
    enum {ENCW = 0, ENCB, LOGDT, CRE, CIM, LOGARE, AIM, DD,
          CONVW, CONVB, LNG, LNB, D1W, D1B, D2W, D2B};

    char* p = (char*)d_ws;
    auto alloc = [&](size_t bytes) {
        char* r = p; p += (bytes + 255) & ~(size_t)255; return r;
    };
    float* kW    = (float*)alloc(128 * 512 * 4);
    float* kS    = (float*)alloc(128 * 64 * 4);
    float* sents = (float*)alloc(512 * 256 * 4);
    float* hbar  = (float*)alloc(512 * 256 * 4);
    float* su    = (float*)alloc(512 * 128 * 4);
    float* subhl = (float*)alloc(512 * 128 * 4);
    float* sy    = (float*)alloc(512 * 128 * 4);
    float* szb   = (float*)alloc(512 * 128 * 4);
    float* sxt   = (float*)alloc(512 * 128 * 4);
    float* sh    = (float*)alloc(512 * 256 * 4);
    f16* encWT   = (f16*)alloc(128 * 256 * 2);
    f16* convWT  = (f16*)alloc(256 * 128 * 2);
    f16* d1WT    = (f16*)alloc(256 * 128 * 2);
    f16* tf      = (f16*)alloc(4194304 * 2);

    long avail = (long)ws_size - (long)(p - (char*)d_ws);
    int SC = 512;
    while (SC > 1 && 3L * SC * 65536 * 2 + 1024 > avail) SC >>= 1;
    int nch = 512 / SC;
    f16* u_c  = (f16*)alloc((size_t)SC * 65536 * 2);
    f16* y_c  = (f16*)alloc((size_t)SC * 65536 * 2);
    f16* xt_c = (f16*)alloc((size_t)SC * 65536 * 2);

    // ---- precompute ----
    hipMemsetAsync(hbar, 0, 512 * 256 * 4, stream);
    s4k_kernel<<<256, 256, 0, stream>>>(
        kW, wp[LOGDT], wp[CRE], wp[CIM], wp[LOGARE], wp[AIM], 512);
    s4k_kernel<<<32, 256, 0, stream>>>(
        kS, sp[LOGDT], sp[CRE], sp[CIM], sp[LOGARE], sp[AIM], 64);
    pack_t_kernel<<<128, 256, 0, stream>>>(encWT, wp[ENCW], 128, 256);
    pack_n_kernel<<<128, 256, 0, stream>>>(convWT, wp[CONVW], 32768);
    pack_t_kernel<<<128, 256, 0, stream>>>(d1WT, wp[D1W], 256, 128);
    toep_kernel<<<16384, 256, 0, stream>>>(tf, kW);

    // ================= word level (f16 MFMA) =================
    for (int c = 0; c < nch; ++c) {
        long tok_base = (long)c * SC * 512;
        enc_mfma<<<SC * 8, 256, 0, stream>>>(
            emb, ids, tok_base, encWT, wp[ENCB], u_c);
        conv_mfma<<<dim3(128, (SC + 63) / 64, 8), 256, 0, stream>>>(
            u_c, tf, wp[DD], y_c, SC);
        glu_mfma<<<dim3(SC, 8), 256, 0, stream>>>(
            y_c, u_c, convWT, wp[CONVB], wp[LNG], wp[LNB], xt_c);
        d1_mfma<<<SC * 8, 256, 0, stream>>>(
            xt_c, d1WT, wp[D1B], hbar, tok_base);
    }
    // d2 on pooled h (pool-before-d2 exact: d2 linear)
    gemm_kernel<<<dim3(8, 2), 256, 0, stream>>>(
        hbar, nullptr, wp[D2W], wp[D2B], sents, nullptr, 0, 256, 256, 0, 0);

    // ================= sentence level (f32) =================
    gemm_kernel<<<dim3(8, 1), 256, 0, stream>>>(
        sents, nullptr, sp[ENCW], sp[ENCB], su, nullptr, 0, 256, 128, 0, 0);
    transpose_kernel<<<dim3(8, 2, 4), 256, 0, stream>>>(su, subhl, 64, 128);
    conv_kernel<<<dim3(128, 1, 1), 256, 0, stream>>>(subhl, kS, sy, 8, 64);
    skipgelu_kernel<<<256, 256, 0, stream>>>(sy, subhl, sp[DD], 6, 8L * 128 * 64);
    glu_kernel<<<dim3(8, 2, 1), 256, 0, stream>>>(
        sp[CONVW], sp[CONVB], sy, subhl, szb, 64);
    ln_kernel<<<dim3(8, 1), 256, 0, stream>>>(szb, sp[LNG], sp[LNB], sxt, 64);
    gemm_kernel<<<dim3(8, 2), 256, 0, stream>>>(
        sxt, nullptr, sp[D1W], sp[D1B], sh, nullptr, 0, 128, 256, 1, 0);
    gemm_kernel<<<dim3(8, 2), 256, 0, stream>>>(
        sh, nullptr, sp[D2W], sp[D2B], (float*)d_out, nullptr, 0, 256, 256, 0, 0);
}